// Round 8
// baseline (468.194 us; speedup 1.0000x reference)
//
#include <hip/hip_runtime.h>
#include <hip/hip_bf16.h>

#define NB 8
#define NT 256
#define NL 64
#define ND 768

typedef __attribute__((ext_vector_type(4))) float f32x4;
typedef __attribute__((ext_vector_type(8))) short bf16x8;

__device__ __forceinline__ short f2bs(float f) {
    __hip_bfloat16 h = __float2bfloat16(f);
    return *reinterpret_cast<short*>(&h);
}
__device__ __forceinline__ unsigned pack2(float a, float b) {
    return (unsigned)(ushort)f2bs(a) | ((unsigned)(ushort)f2bs(b) << 16);
}
__device__ __forceinline__ float bs2f(ushort u) {
    union { unsigned u; float f; } x; x.u = ((unsigned)u) << 16;
    return x.f;
}

// ---------------- Kernel 1: k/v projections (fp32 tiled GEMM) ----------------
__global__ __launch_bounds__(256) void proj_kernel(
    const float* __restrict__ E, const float* __restrict__ Wk,
    const float* __restrict__ Wv, float* __restrict__ kws,
    float* __restrict__ vws)
{
    const float* W = (blockIdx.z == 0) ? Wk : Wv;
    float* O       = (blockIdx.z == 0) ? kws : vws;

    __shared__ float As[16][68];
    __shared__ float Bs[16][68];

    const int tid = threadIdx.x;
    const int m0 = blockIdx.x * 64;
    const int e0 = blockIdx.y * 64;
    const int ty = tid >> 4;
    const int tx = tid & 15;
    const int mm = tid >> 2;
    const int c4 = tid & 3;

    float acc[4][4];
    #pragma unroll
    for (int i = 0; i < 4; ++i)
        #pragma unroll
        for (int j = 0; j < 4; ++j) acc[i][j] = 0.f;

    for (int k0 = 0; k0 < ND; k0 += 16) {
        float4 a = *(const float4*)(E + (size_t)(m0 + mm) * ND + k0 + c4 * 4);
        float4 b = *(const float4*)(W + (size_t)(e0 + mm) * ND + k0 + c4 * 4);
        As[c4*4+0][mm] = a.x; As[c4*4+1][mm] = a.y;
        As[c4*4+2][mm] = a.z; As[c4*4+3][mm] = a.w;
        Bs[c4*4+0][mm] = b.x; Bs[c4*4+1][mm] = b.y;
        Bs[c4*4+2][mm] = b.z; Bs[c4*4+3][mm] = b.w;
        __syncthreads();
        #pragma unroll
        for (int kk = 0; kk < 16; ++kk) {
            float4 av = *(const float4*)&As[kk][ty * 4];
            float4 bv = *(const float4*)&Bs[kk][tx * 4];
            float a4[4] = {av.x, av.y, av.z, av.w};
            float b4[4] = {bv.x, bv.y, bv.z, bv.w};
            #pragma unroll
            for (int i = 0; i < 4; ++i)
                #pragma unroll
                for (int j = 0; j < 4; ++j) acc[i][j] += a4[i] * b4[j];
        }
        __syncthreads();
    }
    #pragma unroll
    for (int i = 0; i < 4; ++i) {
        float4 o;
        o.x = acc[i][0]; o.y = acc[i][1]; o.z = acc[i][2]; o.w = acc[i][3];
        *(float4*)(O + (size_t)(m0 + ty * 4 + i) * ND + e0 + tx * 4) = o;
    }
}

// ---------------- Kernel 2: fused segmented linear attention ----------------
// One 512-thread (8-wave) block per (b,t). tok read from HBM exactly once into
// a persistent bf16 LDS cache; residual taken from the cache.
__global__ __launch_bounds__(512) void fused_kernel(
    const int* __restrict__ spk, const float* __restrict__ tok,
    const float* __restrict__ kws, const float* __restrict__ vws,
    float* __restrict__ out)
{
    __shared__ int mlist[NT];
    __shared__ int wavecnt[8];
    __shared__ ushort tokc[NL * ND];     // 96 KB persistent tok bf16, swizzled
    __shared__ ushort Vt[2][64 * 64];    // 16 KB v slab dbuf
    __shared__ ushort kT[128 * 64];      // 16 KB kT strip
    __shared__ ushort Sb[64 * 64];       //  8 KB S bf16

    const int bt  = blockIdx.x;
    const int b   = bt >> 8;
    const int t   = bt & 255;
    const int tid = threadIdx.x;

    // ---- Phase 0: same-speaker prefix list (8 waves) ----
    const int tgt = spk[b * NT + t];
    int my = -1;
    if (tid <= t) my = spk[b * NT + tid];
    const bool match = (tid <= t) && (my == tgt);
    unsigned long long bal = __ballot(match);
    const int lane = tid & 63, w = tid >> 6;
    if (lane == 0) wavecnt[w] = __popcll(bal);
    __syncthreads();
    int off = 0, n = 0;
    #pragma unroll
    for (int ww = 0; ww < 8; ++ww) { if (ww < w) off += wavecnt[ww]; n += wavecnt[ww]; }
    const int before = __popcll(bal & ((1ull << lane) - 1ull));
    if (match) mlist[off + before] = tid;
    __syncthreads();

    const int fr = lane & 15;
    const int fq = lane >> 4;
    const int band = w >> 1;          // 0..3: 16-row output band
    const int half = w & 1;           // tile split along j / out-col
    const int row2 = tid >> 4;        // 0..31 staging row (and row+32)
    const int c4   = tid & 15;        // staging float4 col

    const size_t tokbase = (size_t)bt * NL * ND;
    const float* vbase = vws + (size_t)b * NT * ND;
    const float* kbase = kws + (size_t)b * NT * ND;
    const f32x4 z4 = {0.f, 0.f, 0.f, 0.f};

    const int arow = band * 16 + fr;
    const int asw  = (arow & 7) << 3;
    const float* gt0 = tok + tokbase + (size_t)row2 * ND;
    const float* gt1 = tok + tokbase + (size_t)(row2 + 32) * ND;

    const int nchunk = (n + 63) >> 6;
    for (int cc = 0; cc < nchunk; ++cc) {
        const int j0 = cc * 64;

        // ---- Phase 1: S = tok @ v^T (12 slabs of 64 cols, Vt dbuf) ----
        const int jj0 = j0 + row2, jj1 = j0 + row2 + 32;
        const float* gv0 = vbase + (size_t)mlist[jj0 < n ? jj0 : n - 1] * ND;
        const float* gv1 = vbase + (size_t)mlist[jj1 < n ? jj1 : n - 1] * ND;

        f32x4 accS[2] = {z4, z4};
        float4 tR[2][2], vR[2][2];
        tR[0][0] = *(const float4*)(gt0 + c4 * 4);
        tR[0][1] = *(const float4*)(gt1 + c4 * 4);
        vR[0][0] = *(const float4*)(gv0 + c4 * 4);
        vR[0][1] = *(const float4*)(gv1 + c4 * 4);

        #pragma unroll
        for (int dt = 0; dt < 12; ++dt) {
            const int cur = dt & 1, nxt = cur ^ 1;
            if (dt < 11) {   // issue next slab; stays in flight over barrier+MFMA
                const int c0 = (dt + 1) * 64 + c4 * 4;
                tR[nxt][0] = *(const float4*)(gt0 + c0);
                tR[nxt][1] = *(const float4*)(gt1 + c0);
                vR[nxt][0] = *(const float4*)(gv0 + c0);
                vR[nxt][1] = *(const float4*)(gv1 + c0);
            }
            #pragma unroll
            for (int pr = 0; pr < 2; ++pr) {
                const int r = row2 + 32 * pr;
                const int inner = (c4 * 4) ^ ((r & 7) << 3);
                uint2 tw; tw.x = pack2(tR[cur][pr].x, tR[cur][pr].y);
                tw.y = pack2(tR[cur][pr].z, tR[cur][pr].w);
                uint2 vw; vw.x = pack2(vR[cur][pr].x, vR[cur][pr].y);
                vw.y = pack2(vR[cur][pr].z, vR[cur][pr].w);
                *(uint2*)&tokc[r * ND + dt * 64 + inner] = tw;
                *(uint2*)&Vt[cur][r * 64 + inner] = vw;
            }
            __syncthreads();
            #pragma unroll
            for (int ks = 0; ks < 2; ++ks) {
                bf16x8 af = *(const bf16x8*)&tokc[arow * ND + dt * 64 + ((ks * 32 + fq * 8) ^ asw)];
                #pragma unroll
                for (int j2 = 0; j2 < 2; ++j2) {
                    const int brow = (half * 2 + j2) * 16 + fr;
                    bf16x8 bv = *(const bf16x8*)&Vt[cur][brow * 64 + ((ks * 32 + fq * 8) ^ ((brow & 7) << 3))];
                    accS[j2] = __builtin_amdgcn_mfma_f32_16x16x32_bf16(af, bv, accS[j2], 0, 0, 0);
                }
            }
        }

        // S -> Sb (C layout: col=lane&15, row=(lane>>4)*4+reg)
        #pragma unroll
        for (int j2 = 0; j2 < 2; ++j2)
            #pragma unroll
            for (int i = 0; i < 4; ++i) {
                const int r = band * 16 + fq * 4 + i;
                const int c = (half * 2 + j2) * 16 + fr;
                Sb[(r * 64 + c) ^ ((r & 7) << 3)] = (ushort)f2bs(accS[j2][i]);
            }

        // ---- Phase 2: out = residual + S @ K (6 strips of 128 cols) ----
        const int g0r = (jj0 < n) ? mlist[jj0] : -1;
        const int g1r = (jj1 < n) ? mlist[jj1] : -1;
        const float* gk0 = (g0r >= 0) ? kbase + (size_t)g0r * ND : nullptr;
        const float* gk1 = (g1r >= 0) ? kbase + (size_t)g1r * ND : nullptr;

        f32x4 kR[2][4];
        #pragma unroll
        for (int pc = 0; pc < 2; ++pc) {
            kR[0][pc]     = gk0 ? *(const f32x4*)(gk0 + (c4 + 16 * pc) * 4) : z4;
            kR[0][2 + pc] = gk1 ? *(const f32x4*)(gk1 + (c4 + 16 * pc) * 4) : z4;
        }

        #pragma unroll
        for (int st = 0; st < 6; ++st) {
            const int cur = st & 1, nxt = cur ^ 1;
            if (st < 5) {   // prefetch next strip's k rows
                const int c0 = (st + 1) * 128;
                #pragma unroll
                for (int pc = 0; pc < 2; ++pc) {
                    kR[nxt][pc]     = gk0 ? *(const f32x4*)(gk0 + c0 + (c4 + 16 * pc) * 4) : z4;
                    kR[nxt][2 + pc] = gk1 ? *(const f32x4*)(gk1 + c0 + (c4 + 16 * pc) * 4) : z4;
                }
            }
            if (st > 0) __syncthreads();   // prior strip's kT reads done
            // stage kT [128 dc][64 j]
            #pragma unroll
            for (int pr = 0; pr < 2; ++pr)
                #pragma unroll
                for (int pc = 0; pc < 2; ++pc)
                    #pragma unroll
                    for (int e = 0; e < 4; ++e) {
                        const int dc = (c4 + 16 * pc) * 4 + e;
                        const int j = row2 + 32 * pr;
                        kT[dc * 64 + (j ^ ((dc & 7) << 3))] = (ushort)f2bs(kR[cur][pr * 2 + pc][e]);
                    }
            // residual init at C-layout positions
            f32x4 acco[4];
            if (cc == 0) {
                #pragma unroll
                for (int c = 0; c < 4; ++c)
                    #pragma unroll
                    for (int i = 0; i < 4; ++i) {
                        const int r = band * 16 + fq * 4 + i;
                        const int C = st * 128 + (half * 4 + c) * 16 + fr;
                        acco[c][i] = bs2f(tokc[r * ND + (C & ~63) + ((C & 63) ^ ((r & 7) << 3))]);
                    }
            } else {
                #pragma unroll
                for (int c = 0; c < 4; ++c)
                    #pragma unroll
                    for (int i = 0; i < 4; ++i) {
                        const int r = band * 16 + fq * 4 + i;
                        const int C = st * 128 + (half * 4 + c) * 16 + fr;
                        acco[c][i] = out[tokbase + (size_t)r * ND + C];
                    }
            }
            __syncthreads();   // kT visible (and Sb on first strip)
            #pragma unroll
            for (int ks = 0; ks < 2; ++ks) {
                bf16x8 af = *(const bf16x8*)&Sb[(arow * 64 + ks * 32 + fq * 8) ^ asw];
                #pragma unroll
                for (int c = 0; c < 4; ++c) {
                    const int brow = (half * 4 + c) * 16 + fr;
                    bf16x8 bv = *(const bf16x8*)&kT[brow * 64 + ((ks * 32 + fq * 8) ^ ((brow & 7) << 3))];
                    acco[c] = __builtin_amdgcn_mfma_f32_16x16x32_bf16(af, bv, acco[c], 0, 0, 0);
                }
            }
            // store (16-lane groups cover contiguous 64B)
            #pragma unroll
            for (int c = 0; c < 4; ++c)
                #pragma unroll
                for (int i = 0; i < 4; ++i) {
                    const int r = band * 16 + fq * 4 + i;
                    const int C = st * 128 + (half * 4 + c) * 16 + fr;
                    out[tokbase + (size_t)r * ND + C] = acco[c][i];
                }
        }
    }
}

extern "C" void kernel_launch(void* const* d_in, const int* in_sizes, int n_in,
                              void* d_out, int out_size, void* d_ws, size_t ws_size,
                              hipStream_t stream) {
    const int*   spk = (const int*)d_in[1];
    const float* tok = (const float*)d_in[2];
    const float* edu = (const float*)d_in[3];
    const float* Wk  = (const float*)d_in[4];
    const float* Wv  = (const float*)d_in[5];

    const size_t kv_floats = (size_t)NB * NT * ND;
    float* kws = (float*)d_ws;
    float* vws = kws + kv_floats;
    float* outp = (float*)d_out;

    dim3 g1(2048 / 64, ND / 64, 2);
    proj_kernel<<<g1, 256, 0, stream>>>(edu, Wk, Wv, kws, vws);
    fused_kernel<<<NB * NT, 512, 0, stream>>>(spk, tok, kws, vws, outp);
}

// Round 9
// 369.783 us; speedup vs baseline: 1.2661x; 1.2661x over previous
//
#include <hip/hip_runtime.h>
#include <hip/hip_bf16.h>

#define NB 8
#define NT 256
#define NL 64
#define ND 768

typedef __attribute__((ext_vector_type(4))) float f32x4;
typedef __attribute__((ext_vector_type(8))) short bf16x8;

__device__ __forceinline__ short f2bs(float f) {
    __hip_bfloat16 h = __float2bfloat16(f);
    return *reinterpret_cast<short*>(&h);
}
__device__ __forceinline__ unsigned pack2(float a, float b) {
    return (unsigned)(ushort)f2bs(a) | ((unsigned)(ushort)f2bs(b) << 16);
}
__device__ __forceinline__ bf16x8 cvt8(float4 x, float4 y) {
    bf16x8 r;
    r[0] = f2bs(x.x); r[1] = f2bs(x.y); r[2] = f2bs(x.z); r[3] = f2bs(x.w);
    r[4] = f2bs(y.x); r[5] = f2bs(y.y); r[6] = f2bs(y.z); r[7] = f2bs(y.w);
    return r;
}

// raw barrier: LDS-writes fenced, global loads stay in flight (no vmcnt drain)
__device__ __forceinline__ void bar_lds() {
    asm volatile("s_waitcnt lgkmcnt(0)" ::: "memory");
    __builtin_amdgcn_s_barrier();
    asm volatile("" ::: "memory");
}
__device__ __forceinline__ void bar_only() {
    asm volatile("" ::: "memory");
    __builtin_amdgcn_s_barrier();
    asm volatile("" ::: "memory");
}

// ---------------- Kernel 1: k/v projections (fp32 tiled GEMM) ----------------
__global__ __launch_bounds__(256) void proj_kernel(
    const float* __restrict__ E, const float* __restrict__ Wk,
    const float* __restrict__ Wv, float* __restrict__ kws,
    float* __restrict__ vws)
{
    const float* W = (blockIdx.z == 0) ? Wk : Wv;
    float* O       = (blockIdx.z == 0) ? kws : vws;

    __shared__ float As[16][68];
    __shared__ float Bs[16][68];

    const int tid = threadIdx.x;
    const int m0 = blockIdx.x * 64;
    const int e0 = blockIdx.y * 64;
    const int ty = tid >> 4;
    const int tx = tid & 15;
    const int mm = tid >> 2;
    const int c4 = tid & 3;

    float acc[4][4];
    #pragma unroll
    for (int i = 0; i < 4; ++i)
        #pragma unroll
        for (int j = 0; j < 4; ++j) acc[i][j] = 0.f;

    for (int k0 = 0; k0 < ND; k0 += 16) {
        float4 a = *(const float4*)(E + (size_t)(m0 + mm) * ND + k0 + c4 * 4);
        float4 b = *(const float4*)(W + (size_t)(e0 + mm) * ND + k0 + c4 * 4);
        As[c4*4+0][mm] = a.x; As[c4*4+1][mm] = a.y;
        As[c4*4+2][mm] = a.z; As[c4*4+3][mm] = a.w;
        Bs[c4*4+0][mm] = b.x; Bs[c4*4+1][mm] = b.y;
        Bs[c4*4+2][mm] = b.z; Bs[c4*4+3][mm] = b.w;
        __syncthreads();
        #pragma unroll
        for (int kk = 0; kk < 16; ++kk) {
            float4 av = *(const float4*)&As[kk][ty * 4];
            float4 bv = *(const float4*)&Bs[kk][tx * 4];
            float a4[4] = {av.x, av.y, av.z, av.w};
            float b4[4] = {bv.x, bv.y, bv.z, bv.w};
            #pragma unroll
            for (int i = 0; i < 4; ++i)
                #pragma unroll
                for (int j = 0; j < 4; ++j) acc[i][j] += a4[i] * b4[j];
        }
        __syncthreads();
    }
    #pragma unroll
    for (int i = 0; i < 4; ++i) {
        float4 o;
        o.x = acc[i][0]; o.y = acc[i][1]; o.z = acc[i][2]; o.w = acc[i][3];
        *(float4*)(O + (size_t)(m0 + ty * 4 + i) * ND + e0 + tx * 4) = o;
    }
}

// ---------------- Kernel 2a: S = tok @ v^T ----------------------------------
// Direct-global A-fragments (line-efficient), v staged coalesced in LDS,
// raw barriers (loads survive), 1-slab register prefetch.
__global__ __launch_bounds__(256, 4) void s_kernel(
    const int* __restrict__ spk, const float* __restrict__ tok,
    const float* __restrict__ vws, ushort* __restrict__ S_ws,
    int* __restrict__ mlistw)
{
    __shared__ int mlist[NT];
    __shared__ int wavecnt[4];
    __shared__ ushort Vt[4096];      // v slab [64 j][64 d] bf16, swizzled
    __shared__ ushort Sb[4096];      // S [64 l][64 j] bf16, swizzled

    const int bt  = blockIdx.x;
    const int b   = bt >> 8;
    const int t   = bt & 255;
    const int tid = threadIdx.x;

    // ---- Phase 0: same-speaker prefix list ----
    const int tgt = spk[b * NT + t];
    int my = -1;
    if (tid <= t) my = spk[b * NT + tid];
    const bool match = (tid <= t) && (my == tgt);
    unsigned long long bal = __ballot(match);
    const int lane = tid & 63, w = tid >> 6;
    if (lane == 0) wavecnt[w] = __popcll(bal);
    __syncthreads();
    int off = 0;
    #pragma unroll
    for (int ww = 0; ww < 4; ++ww) if (ww < w) off += wavecnt[ww];
    const int n = wavecnt[0] + wavecnt[1] + wavecnt[2] + wavecnt[3];
    const int before = __popcll(bal & ((1ull << lane) - 1ull));
    if (match) mlist[off + before] = tid;
    __syncthreads();

    // export mlist + n for b_kernel
    mlistw[bt * 260 + tid] = (tid < n) ? mlist[tid] : 0;
    if (tid == 0) mlistw[bt * 260 + 256] = n;

    const int fr = lane & 15;
    const int fq = lane >> 4;
    const int row = tid >> 2;        // v staging row 0..63
    const int q   = tid & 3;         // 4 lanes per row
    const int rsw = (row & 7) << 3;

    const size_t tokbase = (size_t)bt * NL * ND;
    const float* vbase = vws + (size_t)b * NT * ND;
    const float* tp = tok + tokbase + (size_t)(w * 16 + fr) * ND;   // A row
    const f32x4 z4 = {0.f, 0.f, 0.f, 0.f};

    const int arow = w * 16 + fr;
    const int asw  = (arow & 7) << 3;

    const int nchunk = (n + 63) >> 6;
    for (int cc = 0; cc < nchunk; ++cc) {
        const int j0 = cc * 64;
        const int jj = j0 + row;
        const float* gv = vbase + (size_t)mlist[jj < n ? jj : n - 1] * ND;

        f32x4 accS[4];
        #pragma unroll
        for (int jt = 0; jt < 4; ++jt) accS[jt] = z4;

        float4 va[2][4], aR[2][4];
        #pragma unroll
        for (int p = 0; p < 4; ++p)
            va[0][p] = *(const float4*)(gv + (q + 4 * p) * 4);
        #pragma unroll
        for (int ks = 0; ks < 2; ++ks) {
            aR[0][2 * ks]     = *(const float4*)(tp + ks * 32 + fq * 8);
            aR[0][2 * ks + 1] = *(const float4*)(tp + ks * 32 + fq * 8 + 4);
        }

        #pragma unroll
        for (int dt = 0; dt < 12; ++dt) {
            const int cur = dt & 1, nxt = cur ^ 1;
            // stage v slab (compiler waits vmcnt for va[cur] here)
            #pragma unroll
            for (int p = 0; p < 4; ++p) {
                const int co = (q + 4 * p) * 4;
                uint2 vw;
                vw.x = pack2(va[cur][p].x, va[cur][p].y);
                vw.y = pack2(va[cur][p].z, va[cur][p].w);
                *(uint2*)&Vt[row * 64 + (co ^ rsw)] = vw;
            }
            if (dt < 11) {   // prefetch next v slab — stays in flight across barrier
                const int c0 = (dt + 1) * 64;
                #pragma unroll
                for (int p = 0; p < 4; ++p)
                    va[nxt][p] = *(const float4*)(gv + c0 + (q + 4 * p) * 4);
            }
            bar_lds();
            if (dt < 11) {   // prefetch next A fragments — hidden under MFMA
                const int c0 = (dt + 1) * 64;
                #pragma unroll
                for (int ks = 0; ks < 2; ++ks) {
                    aR[nxt][2 * ks]     = *(const float4*)(tp + c0 + ks * 32 + fq * 8);
                    aR[nxt][2 * ks + 1] = *(const float4*)(tp + c0 + ks * 32 + fq * 8 + 4);
                }
            }
            #pragma unroll
            for (int ks = 0; ks < 2; ++ks) {
                bf16x8 af = cvt8(aR[cur][2 * ks], aR[cur][2 * ks + 1]);
                #pragma unroll
                for (int jt = 0; jt < 4; ++jt) {
                    const int brow = jt * 16 + fr;
                    bf16x8 bv = *(const bf16x8*)&Vt[brow * 64 + ((ks * 32 + fq * 8) ^ ((brow & 7) << 3))];
                    accS[jt] = __builtin_amdgcn_mfma_f32_16x16x32_bf16(af, bv, accS[jt], 0, 0, 0);
                }
            }
            bar_only();      // Vt reads done before next overwrite
        }

        // accS -> Sb (C layout: col=lane&15, row=(lane>>4)*4+reg), then dump
        #pragma unroll
        for (int jt = 0; jt < 4; ++jt) {
            #pragma unroll
            for (int i = 0; i < 4; ++i) {
                const int r = w * 16 + fq * 4 + i;
                const int c = jt * 16 + fr;
                Sb[(r * 64 + c) ^ ((r & 7) << 3)] = (ushort)f2bs(accS[jt][i]);
            }
        }
        bar_lds();
        ushort* dst = S_ws + ((size_t)bt * 4 + cc) * 4096;
        #pragma unroll
        for (int g = 0; g < 2; ++g) {
            const int wsg = g * 256 + tid;
            const int r = wsg >> 3, c8 = wsg & 7;
            *(f32x4*)&dst[(size_t)wsg * 8] = *(const f32x4*)&Sb[(r * 64 + c8 * 8) ^ ((r & 7) << 3)];
        }
        bar_only();
    }
}

// ---------------- Kernel 2b: out = tok + S @ K, one 128-col strip per block --
__global__ __launch_bounds__(256, 4) void b_kernel(
    const float* __restrict__ tok, const float* __restrict__ kws,
    const ushort* __restrict__ S_ws, const int* __restrict__ mlistw,
    float* __restrict__ out)
{
    __shared__ ushort Sb[4096];    // S bf16 [64 l][64 j], swizzled
    __shared__ ushort kT[8192];    // kT bf16 [128 dc][64 j], swizzled

    const int bt  = blockIdx.x;
    const int st  = blockIdx.y;
    const int b   = bt >> 8;
    const int tid = threadIdx.x;
    const int lane = tid & 63, w = tid >> 6;

    const int n = mlistw[bt * 260 + 256];

    const int fr = lane & 15;
    const int fq = lane >> 4;
    const int jr = tid >> 2;       // k-row owner (0..63)
    const int q  = tid & 3;        // 4 lanes per row
    const size_t tokbase = (size_t)bt * NL * ND;
    const float* kbase = kws + (size_t)b * NT * ND;
    const f32x4 zf = {0.f, 0.f, 0.f, 0.f};

    // residual init at C-layout positions (issued early, long in flight)
    f32x4 acco[8];
    {
        const float* rbp = tok + tokbase + (size_t)(w * 16 + fq * 4) * ND + st * 128 + fr;
        #pragma unroll
        for (int ct = 0; ct < 8; ++ct)
            #pragma unroll
            for (int i = 0; i < 4; ++i)
                acco[ct][i] = rbp[(size_t)i * ND + ct * 16];
    }

    const int nchunk = (n + 63) >> 6;
    for (int cc = 0; cc < nchunk; ++cc) {
        const int j0 = cc * 64;
        const ushort* src = S_ws + ((size_t)bt * 4 + cc) * 4096;
        f32x4 sv0 = *(const f32x4*)&src[(size_t)tid * 8];
        f32x4 sv1 = *(const f32x4*)&src[(size_t)(256 + tid) * 8];
        const int jj = j0 + jr;
        const int g = (jj < n) ? mlistw[bt * 260 + jj] : -1;
        f32x4 kreg[8];
        #pragma unroll
        for (int p = 0; p < 8; ++p)
            kreg[p] = (g >= 0)
                ? *(const f32x4*)(kbase + (size_t)g * ND + st * 128 + (q + 4 * p) * 4)
                : zf;

        if (cc > 0) bar_only();   // prior MFMA LDS reads done before overwrite
        {
            int wsg = tid, r = wsg >> 3, c8 = wsg & 7;
            *(f32x4*)&Sb[(r * 64 + c8 * 8) ^ ((r & 7) << 3)] = sv0;
            wsg = 256 + tid; r = wsg >> 3; c8 = wsg & 7;
            *(f32x4*)&Sb[(r * 64 + c8 * 8) ^ ((r & 7) << 3)] = sv1;
        }
        #pragma unroll
        for (int p = 0; p < 8; ++p) {
            #pragma unroll
            for (int e = 0; e < 4; ++e) {
                const int dc = (q + 4 * p) * 4 + e;
                kT[(dc * 64 + jr) ^ ((dc & 7) << 3)] = (ushort)f2bs(kreg[p][e]);
            }
        }
        bar_lds();

        const int arow = w * 16 + fr;
        #pragma unroll
        for (int ks = 0; ks < 2; ++ks) {
            bf16x8 af = *(const bf16x8*)&Sb[(arow * 64 + ks * 32 + fq * 8) ^ ((arow & 7) << 3)];
            #pragma unroll
            for (int ct = 0; ct < 8; ++ct) {
                const int brow = ct * 16 + fr;
                bf16x8 bv = *(const bf16x8*)&kT[(brow * 64 + ks * 32 + fq * 8) ^ ((brow & 7) << 3)];
                acco[ct] = __builtin_amdgcn_mfma_f32_16x16x32_bf16(af, bv, acco[ct], 0, 0, 0);
            }
        }
    }

    float* ob = out + tokbase + (size_t)(w * 16 + fq * 4) * ND + st * 128 + fr;
    #pragma unroll
    for (int ct = 0; ct < 8; ++ct)
        #pragma unroll
        for (int i = 0; i < 4; ++i)
            ob[(size_t)i * ND + ct * 16] = acco[ct][i];
}

extern "C" void kernel_launch(void* const* d_in, const int* in_sizes, int n_in,
                              void* d_out, int out_size, void* d_ws, size_t ws_size,
                              hipStream_t stream) {
    const int*   spk = (const int*)d_in[1];
    const float* tok = (const float*)d_in[2];
    const float* edu = (const float*)d_in[3];
    const float* Wk  = (const float*)d_in[4];
    const float* Wv  = (const float*)d_in[5];

    const size_t kv_floats = (size_t)NB * NT * ND;
    float* kws = (float*)d_ws;
    float* vws = kws + kv_floats;
    ushort* S_ws = (ushort*)(vws + kv_floats);              // 2048*4*4096 u16 = 64MB
    int* mlistw = (int*)(S_ws + (size_t)NB * NT * 4 * 4096); // 2048*260 ints
    float* outp = (float*)d_out;

    dim3 g1(2048 / 64, ND / 64, 2);
    proj_kernel<<<g1, 256, 0, stream>>>(edu, Wk, Wv, kws, vws);
    s_kernel<<<NB * NT, 256, 0, stream>>>(spk, tok, vws, S_ws, mlistw);
    b_kernel<<<dim3(NB * NT, 6), 256, 0, stream>>>(tok, kws, S_ws, mlistw, outp);
}

// Round 10
// 367.884 us; speedup vs baseline: 1.2727x; 1.0052x over previous
//
#include <hip/hip_runtime.h>
#include <hip/hip_bf16.h>

#define NB 8
#define NT 256
#define NL 64
#define ND 768

typedef __attribute__((ext_vector_type(4))) float f32x4;
typedef __attribute__((ext_vector_type(8))) short bf16x8;

__device__ __forceinline__ short f2bs(float f) {
    __hip_bfloat16 h = __float2bfloat16(f);
    return *reinterpret_cast<short*>(&h);
}
__device__ __forceinline__ unsigned pack2(float a, float b) {
    return (unsigned)(ushort)f2bs(a) | ((unsigned)(ushort)f2bs(b) << 16);
}
__device__ __forceinline__ bf16x8 cvt8(float4 x, float4 y) {
    bf16x8 r;
    r[0] = f2bs(x.x); r[1] = f2bs(x.y); r[2] = f2bs(x.z); r[3] = f2bs(x.w);
    r[4] = f2bs(y.x); r[5] = f2bs(y.y); r[6] = f2bs(y.z); r[7] = f2bs(y.w);
    return r;
}

// raw barrier: LDS-writes fenced, global loads stay in flight (no vmcnt drain)
__device__ __forceinline__ void bar_lds() {
    asm volatile("s_waitcnt lgkmcnt(0)" ::: "memory");
    __builtin_amdgcn_s_barrier();
    asm volatile("" ::: "memory");
}
__device__ __forceinline__ void bar_only() {
    asm volatile("" ::: "memory");
    __builtin_amdgcn_s_barrier();
    asm volatile("" ::: "memory");
}

// ---------------- Kernel 1: k/v projections, bf16 MFMA ----------------------
// O[m,e] = sum_d E[m,d] * W[e,d].  Same A-rows x B-rows structure as s_kernel
// (proven fragment layout).  Output bf16 [2048][768].
__global__ __launch_bounds__(256, 4) void projb_kernel(
    const float* __restrict__ E, const float* __restrict__ Wk,
    const float* __restrict__ Wv, ushort* __restrict__ kb,
    ushort* __restrict__ vb)
{
    const float* W = (blockIdx.z == 0) ? Wk : Wv;
    ushort* O      = (blockIdx.z == 0) ? kb : vb;
    const int m0 = blockIdx.x * 64;
    const int e0 = blockIdx.y * 64;

    __shared__ ushort Wt[4096];   // W slab [64 e][64 d] bf16, swizzled
    __shared__ ushort Sb[4096];   // output tile bf16, swizzled

    const int tid = threadIdx.x;
    const int lane = tid & 63, w = tid >> 6;
    const int fr = lane & 15;
    const int fq = lane >> 4;
    const int row = tid >> 2;       // staging row 0..63
    const int q   = tid & 3;        // 4 lanes per row
    const int rsw = (row & 7) << 3;

    const float* ep = E + (size_t)(m0 + w * 16 + fr) * ND;   // A row direct
    const float* wrow = W + (size_t)(e0 + row) * ND;
    const f32x4 z4 = {0.f, 0.f, 0.f, 0.f};

    f32x4 accS[4];
    #pragma unroll
    for (int jt = 0; jt < 4; ++jt) accS[jt] = z4;

    float4 wv[2][4], aR[2][4];
    #pragma unroll
    for (int p = 0; p < 4; ++p)
        wv[0][p] = *(const float4*)(wrow + (q + 4 * p) * 4);
    #pragma unroll
    for (int ks = 0; ks < 2; ++ks) {
        aR[0][2 * ks]     = *(const float4*)(ep + ks * 32 + fq * 8);
        aR[0][2 * ks + 1] = *(const float4*)(ep + ks * 32 + fq * 8 + 4);
    }

    #pragma unroll
    for (int dt = 0; dt < 12; ++dt) {
        const int cur = dt & 1, nxt = cur ^ 1;
        #pragma unroll
        for (int p = 0; p < 4; ++p) {
            const int co = (q + 4 * p) * 4;
            uint2 ww;
            ww.x = pack2(wv[cur][p].x, wv[cur][p].y);
            ww.y = pack2(wv[cur][p].z, wv[cur][p].w);
            *(uint2*)&Wt[row * 64 + (co ^ rsw)] = ww;
        }
        if (dt < 11) {
            const int c0 = (dt + 1) * 64;
            #pragma unroll
            for (int p = 0; p < 4; ++p)
                wv[nxt][p] = *(const float4*)(wrow + c0 + (q + 4 * p) * 4);
        }
        bar_lds();
        if (dt < 11) {
            const int c0 = (dt + 1) * 64;
            #pragma unroll
            for (int ks = 0; ks < 2; ++ks) {
                aR[nxt][2 * ks]     = *(const float4*)(ep + c0 + ks * 32 + fq * 8);
                aR[nxt][2 * ks + 1] = *(const float4*)(ep + c0 + ks * 32 + fq * 8 + 4);
            }
        }
        #pragma unroll
        for (int ks = 0; ks < 2; ++ks) {
            bf16x8 af = cvt8(aR[cur][2 * ks], aR[cur][2 * ks + 1]);
            #pragma unroll
            for (int jt = 0; jt < 4; ++jt) {
                const int brow = jt * 16 + fr;
                bf16x8 bv = *(const bf16x8*)&Wt[brow * 64 + ((ks * 32 + fq * 8) ^ ((brow & 7) << 3))];
                accS[jt] = __builtin_amdgcn_mfma_f32_16x16x32_bf16(af, bv, accS[jt], 0, 0, 0);
            }
        }
        bar_only();
    }

    // acc -> Sb (C layout), then coalesced uint4 dump to O
    #pragma unroll
    for (int jt = 0; jt < 4; ++jt)
        #pragma unroll
        for (int i = 0; i < 4; ++i) {
            const int r = w * 16 + fq * 4 + i;
            const int c = jt * 16 + fr;
            Sb[(r * 64 + c) ^ ((r & 7) << 3)] = (ushort)f2bs(accS[jt][i]);
        }
    bar_lds();
    #pragma unroll
    for (int g = 0; g < 2; ++g) {
        const int c = g * 256 + tid;          // 0..511 uint4 chunks
        const int r = c >> 3, col8 = c & 7;
        uint4 v = *(const uint4*)&Sb[(r * 64 + col8 * 8) ^ ((r & 7) << 3)];
        *(uint4*)(O + (size_t)(m0 + r) * ND + e0 + col8 * 8) = v;
    }
}

// ---------------- Kernel 2a: S = tok @ v^T (bf16 v, XCD-swizzled) -----------
__global__ __launch_bounds__(256, 4) void s_kernel(
    const int* __restrict__ spk, const float* __restrict__ tok,
    const ushort* __restrict__ vws, ushort* __restrict__ S_ws,
    int* __restrict__ mlistw)
{
    __shared__ int mlist[NT];
    __shared__ int wavecnt[4];
    __shared__ ushort Vt[4096];      // v slab [64 j][64 d] bf16, swizzled
    __shared__ ushort Sb[4096];      // S [64 l][64 j] bf16, swizzled

    // XCD swizzle: XCD x handles bt in [x*256,(x+1)*256) -> one batch per XCD
    const int bt  = (blockIdx.x & 7) * 256 + (blockIdx.x >> 3);
    const int b   = bt >> 8;
    const int t   = bt & 255;
    const int tid = threadIdx.x;

    const int tgt = spk[b * NT + t];
    int my = -1;
    if (tid <= t) my = spk[b * NT + tid];
    const bool match = (tid <= t) && (my == tgt);
    unsigned long long bal = __ballot(match);
    const int lane = tid & 63, w = tid >> 6;
    if (lane == 0) wavecnt[w] = __popcll(bal);
    __syncthreads();
    int off = 0;
    #pragma unroll
    for (int ww = 0; ww < 4; ++ww) if (ww < w) off += wavecnt[ww];
    const int n = wavecnt[0] + wavecnt[1] + wavecnt[2] + wavecnt[3];
    const int before = __popcll(bal & ((1ull << lane) - 1ull));
    if (match) mlist[off + before] = tid;
    __syncthreads();

    mlistw[bt * 260 + tid] = (tid < n) ? mlist[tid] : 0;
    if (tid == 0) mlistw[bt * 260 + 256] = n;

    const int fr = lane & 15;
    const int fq = lane >> 4;
    const int row = tid >> 2;
    const int q   = tid & 3;
    const int rsw = (row & 7) << 3;

    const size_t tokbase = (size_t)bt * NL * ND;
    const ushort* vbase = vws + (size_t)b * NT * ND;
    const float* tp = tok + tokbase + (size_t)(w * 16 + fr) * ND;
    const f32x4 z4 = {0.f, 0.f, 0.f, 0.f};

    const int nchunk = (n + 63) >> 6;
    for (int cc = 0; cc < nchunk; ++cc) {
        const int j0 = cc * 64;
        const int jj = j0 + row;
        const ushort* gv = vbase + (size_t)mlist[jj < n ? jj : n - 1] * ND;

        f32x4 accS[4];
        #pragma unroll
        for (int jt = 0; jt < 4; ++jt) accS[jt] = z4;

        uint4 vu[2][2];
        float4 aR[2][4];
        vu[0][0] = *(const uint4*)(gv + q * 16);
        vu[0][1] = *(const uint4*)(gv + q * 16 + 8);
        #pragma unroll
        for (int ks = 0; ks < 2; ++ks) {
            aR[0][2 * ks]     = *(const float4*)(tp + ks * 32 + fq * 8);
            aR[0][2 * ks + 1] = *(const float4*)(tp + ks * 32 + fq * 8 + 4);
        }

        #pragma unroll
        for (int dt = 0; dt < 12; ++dt) {
            const int cur = dt & 1, nxt = cur ^ 1;
            // stage v slab (raw u16 copy, no cvt)
            *(uint4*)&Vt[row * 64 + ((q * 16) ^ rsw)]     = vu[cur][0];
            *(uint4*)&Vt[row * 64 + ((q * 16 + 8) ^ rsw)] = vu[cur][1];
            if (dt < 11) {
                const int c0 = (dt + 1) * 64;
                vu[nxt][0] = *(const uint4*)(gv + c0 + q * 16);
                vu[nxt][1] = *(const uint4*)(gv + c0 + q * 16 + 8);
            }
            bar_lds();
            if (dt < 11) {
                const int c0 = (dt + 1) * 64;
                #pragma unroll
                for (int ks = 0; ks < 2; ++ks) {
                    aR[nxt][2 * ks]     = *(const float4*)(tp + c0 + ks * 32 + fq * 8);
                    aR[nxt][2 * ks + 1] = *(const float4*)(tp + c0 + ks * 32 + fq * 8 + 4);
                }
            }
            #pragma unroll
            for (int ks = 0; ks < 2; ++ks) {
                bf16x8 af = cvt8(aR[cur][2 * ks], aR[cur][2 * ks + 1]);
                #pragma unroll
                for (int jt = 0; jt < 4; ++jt) {
                    const int brow = jt * 16 + fr;
                    bf16x8 bv = *(const bf16x8*)&Vt[brow * 64 + ((ks * 32 + fq * 8) ^ ((brow & 7) << 3))];
                    accS[jt] = __builtin_amdgcn_mfma_f32_16x16x32_bf16(af, bv, accS[jt], 0, 0, 0);
                }
            }
            bar_only();
        }

        #pragma unroll
        for (int jt = 0; jt < 4; ++jt)
            #pragma unroll
            for (int i = 0; i < 4; ++i) {
                const int r = w * 16 + fq * 4 + i;
                const int c = jt * 16 + fr;
                Sb[(r * 64 + c) ^ ((r & 7) << 3)] = (ushort)f2bs(accS[jt][i]);
            }
        bar_lds();
        ushort* dst = S_ws + ((size_t)bt * 4 + cc) * 4096;
        #pragma unroll
        for (int g = 0; g < 2; ++g) {
            const int wsg = g * 256 + tid;
            const int r = wsg >> 3, c8 = wsg & 7;
            *(f32x4*)&dst[(size_t)wsg * 8] = *(const f32x4*)&Sb[(r * 64 + c8 * 8) ^ ((r & 7) << 3)];
        }
        bar_only();
    }
}

// ---------------- Kernel 2b: out = tok + S @ K (bf16 k, XCD-swizzled) -------
__global__ __launch_bounds__(256, 4) void b_kernel(
    const float* __restrict__ tok, const ushort* __restrict__ kws,
    const ushort* __restrict__ S_ws, const int* __restrict__ mlistw,
    float* __restrict__ out)
{
    __shared__ ushort Sb[4096];
    __shared__ ushort kT[8192];

    // flatten + XCD swizzle: XCD x -> contiguous wgid range -> one batch
    const int i = blockIdx.x;
    const int wgid = (i & 7) * 1536 + (i >> 3);
    const int bt = wgid / 6;
    const int st = wgid % 6;
    const int b   = bt >> 8;
    const int tid = threadIdx.x;
    const int lane = tid & 63, w = tid >> 6;

    const int n = mlistw[bt * 260 + 256];

    const int fr = lane & 15;
    const int fq = lane >> 4;
    const int jr = tid >> 2;
    const int q  = tid & 3;
    const size_t tokbase = (size_t)bt * NL * ND;
    const ushort* kbase = kws + (size_t)b * NT * ND;

    f32x4 acco[8];
    {
        const float* rbp = tok + tokbase + (size_t)(w * 16 + fq * 4) * ND + st * 128 + fr;
        #pragma unroll
        for (int ct = 0; ct < 8; ++ct)
            #pragma unroll
            for (int i2 = 0; i2 < 4; ++i2)
                acco[ct][i2] = rbp[(size_t)i2 * ND + ct * 16];
    }

    const int nchunk = (n + 63) >> 6;
    for (int cc = 0; cc < nchunk; ++cc) {
        const int j0 = cc * 64;
        const ushort* src = S_ws + ((size_t)bt * 4 + cc) * 4096;
        f32x4 sv0 = *(const f32x4*)&src[(size_t)tid * 8];
        f32x4 sv1 = *(const f32x4*)&src[(size_t)(256 + tid) * 8];
        const int jj = j0 + jr;
        const int g = (jj < n) ? mlistw[bt * 260 + jj] : -1;
        uint4 kq[4];
        const uint4 zu = {0u, 0u, 0u, 0u};
        #pragma unroll
        for (int u = 0; u < 4; ++u)
            kq[u] = (g >= 0)
                ? *(const uint4*)(kbase + (size_t)g * ND + st * 128 + q * 32 + u * 8)
                : zu;

        if (cc > 0) bar_only();
        {
            int wsg = tid, r = wsg >> 3, c8 = wsg & 7;
            *(f32x4*)&Sb[(r * 64 + c8 * 8) ^ ((r & 7) << 3)] = sv0;
            wsg = 256 + tid; r = wsg >> 3; c8 = wsg & 7;
            *(f32x4*)&Sb[(r * 64 + c8 * 8) ^ ((r & 7) << 3)] = sv1;
        }
        {
            const ushort* pk = (const ushort*)kq;
            #pragma unroll
            for (int u = 0; u < 4; ++u)
                #pragma unroll
                for (int e = 0; e < 8; ++e) {
                    const int dc = q * 32 + u * 8 + e;
                    kT[(dc * 64 + jr) ^ ((dc & 7) << 3)] = pk[u * 8 + e];
                }
        }
        bar_lds();

        const int arow = w * 16 + fr;
        #pragma unroll
        for (int ks = 0; ks < 2; ++ks) {
            bf16x8 af = *(const bf16x8*)&Sb[(arow * 64 + ks * 32 + fq * 8) ^ ((arow & 7) << 3)];
            #pragma unroll
            for (int ct = 0; ct < 8; ++ct) {
                const int brow = ct * 16 + fr;
                bf16x8 bv = *(const bf16x8*)&kT[(brow * 64 + ks * 32 + fq * 8) ^ ((brow & 7) << 3)];
                acco[ct] = __builtin_amdgcn_mfma_f32_16x16x32_bf16(af, bv, acco[ct], 0, 0, 0);
            }
        }
    }

    float* ob = out + tokbase + (size_t)(w * 16 + fq * 4) * ND + st * 128 + fr;
    #pragma unroll
    for (int ct = 0; ct < 8; ++ct)
        #pragma unroll
        for (int i2 = 0; i2 < 4; ++i2)
            ob[(size_t)i2 * ND + ct * 16] = acco[ct][i2];
}

extern "C" void kernel_launch(void* const* d_in, const int* in_sizes, int n_in,
                              void* d_out, int out_size, void* d_ws, size_t ws_size,
                              hipStream_t stream) {
    const int*   spk = (const int*)d_in[1];
    const float* tok = (const float*)d_in[2];
    const float* edu = (const float*)d_in[3];
    const float* Wk  = (const float*)d_in[4];
    const float* Wv  = (const float*)d_in[5];

    const size_t kv_elems = (size_t)NB * NT * ND;            // 1.57M u16 each
    ushort* kb = (ushort*)d_ws;
    ushort* vb = kb + kv_elems;
    ushort* S_ws = vb + kv_elems;                            // 2048*4*4096 u16 = 64MB
    int* mlistw = (int*)(S_ws + (size_t)NB * NT * 4 * 4096);
    float* outp = (float*)d_out;

    projb_kernel<<<dim3(2048 / 64, ND / 64, 2), 256, 0, stream>>>(edu, Wk, Wv, kb, vb);
    s_kernel<<<NB * NT, 256, 0, stream>>>(spk, tok, vb, S_ws, mlistw);
    b_kernel<<<NB * NT * 6, 256, 0, stream>>>(tok, kb, S_ws, mlistw, outp);
}